// Round 8
// baseline (74.752 us; speedup 1.0000x reference)
//
#include <hip/hip_runtime.h>

typedef _Float16 f16;
typedef _Float16 f16x4 __attribute__((ext_vector_type(4)));
typedef _Float16 f16x8 __attribute__((ext_vector_type(8)));
typedef float f32x4 __attribute__((ext_vector_type(4)));

#define L2E 1.44269504088896340736f

constexpr int D  = 512;
constexpr int S  = 1024;
constexpr int B  = 4;
constexpr int BS = B * S;   // 4096

// workspace layout (bytes); total ~27.3 MB
constexpr size_t OFF_WT   = 0;                               // 4 * 512*512 f16 (WqT,WkT,WvT,WoT)
constexpr size_t OFF_Q16  = OFF_WT  + 4ull * D * D * 2;
constexpr size_t OFF_K16  = OFF_Q16 + (size_t)BS * D * 2;
constexpr size_t OFF_VT   = OFF_K16 + (size_t)BS * D * 2;    // v, transposed: [b*512+n][S]
constexpr size_t OFF_AT   = OFF_VT  + (size_t)BS * D * 2;    // attention output f16 [BS][D]
constexpr size_t OFF_TAB  = OFF_AT  + (size_t)BS * D * 2;    // float [8][1032]
constexpr size_t OFF_COEF = OFF_TAB + 8ull * 1032 * 4;       // float c[8], d[8]; int flag[8]
constexpr size_t OFF_TDH  = OFF_COEF + 256;                  // f16 td, col-permuted, 8.4 MB

// ---------------------------------------------------------------------------
// Kernel 1 "prep": (a) weight transpose+cvt, (b) td f32->f16 col-permuted,
// (c) bias LUT + analytic linearity detection (no atomics).
// grid: [0,256) wtrans | [256,2304) tdconv | 2304 LUT+coef
// ---------------------------------------------------------------------------
__global__ __launch_bounds__(256) void prep(
    const float* __restrict__ Wq, const float* __restrict__ Wk,
    const float* __restrict__ Wv, const float* __restrict__ Wo,
    f16* __restrict__ WT,
    const float* __restrict__ td, f16* __restrict__ tdh,
    const float* __restrict__ Wt1, const float* __restrict__ bt1,
    const float* __restrict__ Wt2, const float* __restrict__ bt2,
    float* __restrict__ tab, float* __restrict__ coef)
{
    __shared__ float tile[64][65];
    __shared__ float w1s[32], b1s[32], w2s[256], b2s[8];

    const int bx = blockIdx.x;
    const int t = threadIdx.x;

    if (bx < 256) {
        // ---- weight transpose ----
        const int z = bx >> 6, xy = bx & 63;
        const float* __restrict__ W = (z == 0) ? Wq : (z == 1) ? Wk : (z == 2) ? Wv : Wo;
        f16* __restrict__ out = WT + (size_t)z * D * D;
        const int k0 = (xy >> 3) * 64, n0 = (xy & 7) * 64;
        for (int i = t; i < 4096; i += 256) {
            int r = i >> 6, c = i & 63;
            tile[r][c] = W[(size_t)(k0 + r) * D + n0 + c];
        }
        __syncthreads();
        for (int i = t; i < 4096; i += 256) {
            int nn = i >> 6, kk = i & 63;
            out[(size_t)(n0 + nn) * D + k0 + kk] = (f16)tile[kk][nn];
        }
    } else if (bx < 2304) {
        // ---- td convert+permute: chunk = 8 dest f16 ----
        const int chunk = (bx - 256) * 256 + t;       // [0, 524288)
        const int row = chunk >> 7;                   // 4096 rows, 128 chunks each
        const int c7 = chunk & 127;
        const int tl = c7 >> 2, gg = c7 & 3;
        const float* __restrict__ src = td + (size_t)row * S + tl * 32;
        float4 a = *reinterpret_cast<const float4*>(src + gg * 4);
        float4 c = *reinterpret_cast<const float4*>(src + 16 + gg * 4);
        f16x8 hv;
        hv[0] = (f16)a.x; hv[1] = (f16)a.y; hv[2] = (f16)a.z; hv[3] = (f16)a.w;
        hv[4] = (f16)c.x; hv[5] = (f16)c.y; hv[6] = (f16)c.z; hv[7] = (f16)c.w;
        *reinterpret_cast<f16x8*>(tdh + (size_t)chunk * 8) = hv;
    } else {
        // ---- bias LUT + coef/flag (no atomics) ----
        if (t < 32) { w1s[t] = Wt1[t]; b1s[t] = bt1[t]; }
        w2s[t] = Wt2[t];
        if (t < 8) b2s[t] = bt2[t];
        __syncthreads();

        const int hh = t >> 5, j = t & 31;

        float f0 = b2s[hh], f1 = b2s[hh];
#pragma unroll 4
        for (int jj = 0; jj < 32; ++jj) {
            float w2 = w2s[jj * 8 + hh];
            f0 += fmaxf(b1s[jj], 0.f) * w2;
            f1 += fmaxf(w1s[jj] + b1s[jj], 0.f) * w2;
        }

        // exact max deviation of the PWL from the chord: check breakpoint u_j
        float devj = 0.f;
        {
            float w1 = w1s[j], b1 = b1s[j];
            float u = (w1 != 0.f) ? (-b1 / w1) : -1.f;
            if (u > 0.f && u < 1.f) {
                float fu = b2s[hh];
#pragma unroll 4
                for (int jj = 0; jj < 32; ++jj)
                    fu += fmaxf(fmaf(u, w1s[jj], b1s[jj]), 0.f) * w2s[jj * 8 + hh];
                devj = fabsf(fu - fmaf(u, f1 - f0, f0)) * L2E;
            }
        }
#pragma unroll
        for (int m = 1; m < 32; m <<= 1)
            devj = fmaxf(devj, __shfl_xor(devj, m));

        if (j == 0) {
            coef[hh]     = (f1 - f0) * L2E;
            coef[8 + hh] = f0 * L2E;
            ((int*)coef)[16 + hh] = (devj < 1e-4f) ? 1 : 0;
        }

        // LUT for the general nonlinear path
        for (int idx = t; idx <= 1024; idx += 256) {
            float tdv = (float)idx * (1.0f / 1024.0f);
            float acc[8];
#pragma unroll
            for (int h2 = 0; h2 < 8; ++h2) acc[h2] = b2s[h2];
#pragma unroll 4
            for (int jj = 0; jj < 32; ++jj) {
                float hvv = fmaxf(fmaf(tdv, w1s[jj], b1s[jj]), 0.f);
#pragma unroll
                for (int h2 = 0; h2 < 8; ++h2) acc[h2] += hvv * w2s[jj * 8 + h2];
            }
#pragma unroll
            for (int h2 = 0; h2 < 8; ++h2)
                tab[h2 * 1032 + idx] = acc[h2] * L2E;
        }
    }
}

// ---------------------------------------------------------------------------
// Kernel 2: fused q/k/v projection GEMM (unchanged).
// ---------------------------------------------------------------------------
__global__ __launch_bounds__(256) void proj_gemm(
    const float* __restrict__ Aq, const float* __restrict__ Ak, const float* __restrict__ Av,
    const f16* __restrict__ WT,
    const float* __restrict__ bq, const float* __restrict__ bk, const float* __restrict__ bv,
    f16* __restrict__ q16, f16* __restrict__ k16, f16* __restrict__ vT, float qscale)
{
    __shared__ f16 As[2][128][40];
    __shared__ f16 Bs[2][64][40];

    const int z = blockIdx.z;
    const float* __restrict__ A    = (z == 0) ? Aq : (z == 1) ? Ak : Av;
    const float* __restrict__ bias = (z == 0) ? bq : (z == 1) ? bk : bv;
    const f16* __restrict__ W      = WT + (size_t)z * D * D;
    const float scale = (z == 0) ? qscale : 1.0f;

    const int t = threadIdx.x;
    const int l = t & 63, w = t >> 6;
    const int i16 = l & 15, g = l >> 4;
    const int wm = w >> 1, wn = w & 1;
    const int m0 = blockIdx.x * 128, n0 = blockIdx.y * 64;

    f32x4 acc[4][2] = {};

    float4 ar[4];
    f16x8  br;
    const int arow = t >> 3, ac4 = t & 7;
    const int brow = t >> 2, bc8 = t & 3;

    auto load_stage = [&](int kt) {
        const int k0 = kt * 32;
#pragma unroll
        for (int r = 0; r < 4; ++r)
            ar[r] = *reinterpret_cast<const float4*>(A + (size_t)(m0 + arow + 32 * r) * D + k0 + ac4 * 4);
        br = *reinterpret_cast<const f16x8*>(W + (size_t)(n0 + brow) * D + k0 + bc8 * 8);
    };
    auto write_stage = [&](int buf) {
#pragma unroll
        for (int r = 0; r < 4; ++r) {
            f16x4 hv;
            hv[0] = (f16)ar[r].x; hv[1] = (f16)ar[r].y; hv[2] = (f16)ar[r].z; hv[3] = (f16)ar[r].w;
            *reinterpret_cast<f16x4*>(&As[buf][arow + 32 * r][ac4 * 4]) = hv;
        }
        *reinterpret_cast<f16x8*>(&Bs[buf][brow][bc8 * 8]) = br;
    };

    load_stage(0);
    write_stage(0);
    __syncthreads();

    for (int kt = 0; kt < 16; ++kt) {
        const int cur = kt & 1;
        if (kt < 15) load_stage(kt + 1);

        f16x8 af[4], bf[2];
#pragma unroll
        for (int i = 0; i < 4; ++i)
            af[i] = *reinterpret_cast<const f16x8*>(&As[cur][wm * 64 + i * 16 + i16][g * 8]);
#pragma unroll
        for (int j = 0; j < 2; ++j)
            bf[j] = *reinterpret_cast<const f16x8*>(&Bs[cur][wn * 32 + j * 16 + i16][g * 8]);
#pragma unroll
        for (int i = 0; i < 4; ++i)
#pragma unroll
            for (int j = 0; j < 2; ++j)
                acc[i][j] = __builtin_amdgcn_mfma_f32_16x16x32_f16(af[i], bf[j], acc[i][j], 0, 0, 0);

        if (kt < 15) write_stage(cur ^ 1);
        __syncthreads();
    }

    float bvv[2];
#pragma unroll
    for (int j = 0; j < 2; ++j) bvv[j] = bias[n0 + wn * 32 + j * 16 + i16];

    if (z < 2) {
        f16* __restrict__ out = (z == 0) ? q16 : k16;
#pragma unroll
        for (int i = 0; i < 4; ++i) {
#pragma unroll
            for (int j = 0; j < 2; ++j) {
                const int nn = n0 + wn * 32 + j * 16 + i16;
#pragma unroll
                for (int e = 0; e < 4; ++e) {
                    const int mr = m0 + wm * 64 + i * 16 + g * 4 + e;
                    out[(size_t)mr * D + nn] = (f16)((acc[i][j][e] + bvv[j]) * scale);
                }
            }
        }
    } else {
#pragma unroll
        for (int i = 0; i < 4; ++i) {
            const int mr = m0 + wm * 64 + i * 16 + g * 4;
            const int bb = mr >> 10, jj = mr & 1023;
#pragma unroll
            for (int j = 0; j < 2; ++j) {
                const int nn = n0 + wn * 32 + j * 16 + i16;
                f16x4 hv;
#pragma unroll
                for (int e = 0; e < 4; ++e) hv[e] = (f16)(acc[i][j][e] + bvv[j]);
                *reinterpret_cast<f16x4*>(vT + ((size_t)(bb * D + nn)) * S + jj) = hv;
            }
        }
    }
}

// ---------------------------------------------------------------------------
// Kernel 3: fused flash attention with temporal bias.
// R7: distance-2 register prefetch (T14).  Two named E/O register sets
// ping-pong: iter jt issues global loads for tile jt+2 and LDS-writes tile
// jt+1 (loaded one full iteration earlier) -> the stage_write's vmcnt waits
// on loads that have had ~1100cy to return (counted vmcnt, not 0).  td
// prefetch moved to the same distance-2 scheme.  Rest unchanged from R5/R6
// (KV-split pairs, flash-decoding combine, swizzled LDS).
// ---------------------------------------------------------------------------
__global__ __launch_bounds__(256, 4) void attn_kernel(
    const f16* __restrict__ q16, const f16* __restrict__ k16, const f16* __restrict__ vT,
    const f16* __restrict__ tdh, const float* __restrict__ tabg, const float* __restrict__ coef,
    f16* __restrict__ out16)
{
    __shared__ __align__(16) f16 Ks[2][2][2048];   // [dbuf][half][32*64]
    __shared__ __align__(16) f16 Vs[2][2][2048];   // [dbuf][half][64*32]
    __shared__ __align__(16) f16 Ps[4][512];
    __shared__ float mlb[2][2][16];                // [pair][m|l][row]

    const int bid = blockIdx.x;
    const int b  = bid & 3;
    const int h  = (bid >> 2) & 7;
    const int qt = bid >> 5;                 // [0,32)

    const int t = threadIdx.x;
    const int w = t >> 6, l = t & 63;
    const int i16 = l & 15, g = l >> 4;
    const int half = w >> 1, pr = w & 1;
    const int qrow = qt * 32 + pr * 16 + i16;

    const float cH = coef[h], dH = coef[8 + h];
    const int lin = ((const int*)coef)[16 + h];
    const float* __restrict__ th = tabg + h * 1032;

    f16x8 qf[2];
#pragma unroll
    for (int kf = 0; kf < 2; ++kf)
        qf[kf] = *reinterpret_cast<const f16x8*>(
            q16 + (size_t)(b * S + qrow) * D + h * 64 + kf * 32 + g * 8);

    float mr = -1e30f, lr = 0.f;
    f32x4 o[4] = {};

    const int krow = t >> 3, kc8 = t & 7;
    const int vdv  = t >> 2, vj8 = t & 3;
    const int kofs = krow * 64 + ((kc8 ^ (krow & 7)) << 3);
    const int vofs = vdv * 32 + ((vj8 ^ (vdv & 3)) << 3);

    auto loadSet = [&](f16x8& k0r, f16x8& k1r, f16x8& v0r, f16x8& v1r, int jt) {
        const f16* kp = k16 + (size_t)(b * S + jt * 32 + krow) * D + h * 64 + kc8 * 8;
        k0r = *reinterpret_cast<const f16x8*>(kp);
        k1r = *reinterpret_cast<const f16x8*>(kp + (size_t)512 * D);
        const f16* vp = vT + (size_t)(b * D + h * 64 + vdv) * S + jt * 32 + vj8 * 8;
        v0r = *reinterpret_cast<const f16x8*>(vp);
        v1r = *reinterpret_cast<const f16x8*>(vp + 512);
    };
    auto writeSet = [&](int buf, const f16x8& k0r, const f16x8& k1r,
                        const f16x8& v0r, const f16x8& v1r) {
        *reinterpret_cast<f16x8*>(&Ks[buf][0][kofs]) = k0r;
        *reinterpret_cast<f16x8*>(&Ks[buf][1][kofs]) = k1r;
        *reinterpret_cast<f16x8*>(&Vs[buf][0][vofs]) = v0r;
        *reinterpret_cast<f16x8*>(&Vs[buf][1][vofs]) = v1r;
    };

    int kro0[2], kro1[2], vro[4];
#pragma unroll
    for (int fj = 0; fj < 2; ++fj) {
        const int rj = fj * 16 + i16;
        kro0[fj] = rj * 64 + ((g ^ (i16 & 7)) << 3);
        kro1[fj] = rj * 64 + (((g + 4) ^ (i16 & 7)) << 3);
    }
#pragma unroll
    for (int fv = 0; fv < 4; ++fv)
        vro[fv] = (fv * 16 + i16) * 32 + ((g ^ (i16 & 3)) << 3);

    const int q2  = (i16 >> 1) & 3;
    const int pw0 = i16 * 32 + ((((g >> 1)    ) ^ q2) << 3) + ((g & 1) << 2);
    const int pw1 = i16 * 32 + ((((g >> 1) + 2) ^ q2) << 3) + ((g & 1) << 2);
    const int prd = i16 * 32 + ((g ^ q2) << 3);

    const f16* __restrict__ tdp = tdh + (size_t)(b * S + qrow) * S + half * 512 + g * 8;

    // one KV-tile step: bias+softmax+PV on buffer `cur` with td regs `tcur`
    auto tile = [&](int cur, f16x8 tcur) {
        f32x4 s[2];
#pragma unroll
        for (int fj = 0; fj < 2; ++fj) {
            f16x8 ka0 = *reinterpret_cast<const f16x8*>(&Ks[cur][half][kro0[fj]]);
            f16x8 ka1 = *reinterpret_cast<const f16x8*>(&Ks[cur][half][kro1[fj]]);
            f32x4 zz = {0.f, 0.f, 0.f, 0.f};
            zz = __builtin_amdgcn_mfma_f32_16x16x32_f16(ka0, qf[0], zz, 0, 0, 0);
            s[fj] = __builtin_amdgcn_mfma_f32_16x16x32_f16(ka1, qf[1], zz, 0, 0, 0);
        }

        float pvv[2][4];
        float tmax = -1e30f;
#pragma unroll
        for (int fj = 0; fj < 2; ++fj)
#pragma unroll
            for (int e = 0; e < 4; ++e) {
                float u = (float)tcur[fj * 4 + e];
                float vsc;
                if (lin) {
                    vsc = fmaf(u, cH, s[fj][e] + dH);
                } else {
                    float x = fminf(fmaxf(u, 0.f), 1.f) * 1024.f;
                    int ix = (int)x;
                    ix = (ix > 1023) ? 1023 : ix;
                    float fr = x - (float)ix;
                    float t0v = th[ix], t1v = th[ix + 1];
                    vsc = s[fj][e] + fmaf(fr, t1v - t0v, t0v);
                }
                pvv[fj][e] = vsc;
                tmax = fmaxf(tmax, vsc);
            }
        tmax = fmaxf(tmax, __shfl_xor(tmax, 16));
        tmax = fmaxf(tmax, __shfl_xor(tmax, 32));
        if (__any(tmax > mr)) {
            float mnew = fmaxf(mr, tmax);
            float alpha = exp2f(mr - mnew);
            mr = mnew;
            lr *= alpha;
#pragma unroll
            for (int fv = 0; fv < 4; ++fv) o[fv] *= alpha;
        }

        float rsum = 0.f;
        f16x4 pq[2];
#pragma unroll
        for (int fj = 0; fj < 2; ++fj)
#pragma unroll
            for (int e = 0; e < 4; ++e) {
                float p = exp2f(pvv[fj][e] - mr);
                rsum += p;
                pq[fj][e] = (f16)p;
            }
        rsum += __shfl_xor(rsum, 16);
        rsum += __shfl_xor(rsum, 32);
        lr += rsum;

        f16* ps = Ps[w];
        *reinterpret_cast<f16x4*>(ps + pw0) = pq[0];
        *reinterpret_cast<f16x4*>(ps + pw1) = pq[1];
        f16x8 pb = *reinterpret_cast<const f16x8*>(ps + prd);

#pragma unroll
        for (int fv = 0; fv < 4; ++fv) {
            f16x8 va = *reinterpret_cast<const f16x8*>(&Vs[cur][half][vro[fv]]);
            o[fv] = __builtin_amdgcn_mfma_f32_16x16x32_f16(va, pb, o[fv], 0, 0, 0);
        }
    };

    // E/O register sets; distance-2 pipeline
    f16x8 skE0, skE1, svE0, svE1, skO0, skO1, svO0, svO1;
    f16x8 tE, tO;

    loadSet(skE0, skE1, svE0, svE1, 0);
    tE = *reinterpret_cast<const f16x8*>(tdp);
    writeSet(0, skE0, skE1, svE0, svE1);
    loadSet(skO0, skO1, svO0, svO1, 1);
    tO = *reinterpret_cast<const f16x8*>(tdp + 32);
    __syncthreads();

    for (int p = 0; p < 8; ++p) {
        // even iter jt = 2p: compute buf0/tE; prefetch tile 2p+2 into E
        {
            f16x8 tcur = tE;
            if (p < 7) {
                loadSet(skE0, skE1, svE0, svE1, 2 * p + 2);
                tE = *reinterpret_cast<const f16x8*>(tdp + (2 * p + 2) * 32);
            }
            tile(0, tcur);
            writeSet(1, skO0, skO1, svO0, svO1);    // tile 2p+1, loaded 1 iter ago
            __syncthreads();
        }
        // odd iter jt = 2p+1: compute buf1/tO; prefetch tile 2p+3 into O
        {
            f16x8 tcur = tO;
            if (p < 7) {
                loadSet(skO0, skO1, svO0, svO1, 2 * p + 3);
                tO = *reinterpret_cast<const f16x8*>(tdp + (2 * p + 3) * 32);
            }
            tile(1, tcur);
            if (p < 7) writeSet(0, skE0, skE1, svE0, svE1);   // tile 2p+2
            __syncthreads();
        }
    }

    // ---- merge halves (flash-decoding combine), then store ----
    float* ob = (float*)&Ks[0][0][0];
    if (w >= 2) {
        float* obp = ob + pr * (16 * 68);
#pragma unroll
        for (int fv = 0; fv < 4; ++fv)
            *reinterpret_cast<f32x4*>(&obp[i16 * 68 + fv * 16 + g * 4]) = o[fv];
        if (g == 0) { mlb[pr][0][i16] = mr; mlb[pr][1][i16] = lr; }
    }
    __syncthreads();
    if (w < 2) {
        const float m1 = mlb[pr][0][i16], l1 = mlb[pr][1][i16];
        const float mm = fmaxf(mr, m1);
        const float a0 = exp2f(mr - mm), a1 = exp2f(m1 - mm);
        const float inv = 1.0f / (lr * a0 + l1 * a1);
        const float* obp = ob + pr * (16 * 68);
#pragma unroll
        for (int fv = 0; fv < 4; ++fv) {
            f32x4 o1 = *reinterpret_cast<const f32x4*>(&obp[i16 * 68 + fv * 16 + g * 4]);
            f16x4 hv;
#pragma unroll
            for (int e = 0; e < 4; ++e) hv[e] = (f16)((o[fv][e] * a0 + o1[e] * a1) * inv);
            *reinterpret_cast<f16x4*>(
                out16 + (size_t)(b * S + qrow) * D + h * 64 + fv * 16 + g * 4) = hv;
        }
    }
}

// ---------------------------------------------------------------------------
// Kernel 4: output projection (unchanged).
// ---------------------------------------------------------------------------
__global__ __launch_bounds__(256) void final_gemm(const f16* __restrict__ A, const f16* __restrict__ WoT,
                                                  const float* __restrict__ bo, float* __restrict__ out)
{
    __shared__ f16 As[2][64][40];
    __shared__ f16 Bs[2][64][40];

    const int t = threadIdx.x;
    const int l = t & 63, w = t >> 6;
    const int i16 = l & 15, g = l >> 4;
    const int wm = w >> 1, wn = w & 1;
    const int m0 = blockIdx.x * 64, n0 = blockIdx.y * 64;

    f32x4 acc[2][2] = {};
    f16x8 ar, br;
    const int srow = t >> 2, sc8 = t & 3;

    auto load_stage = [&](int kt) {
        const int k0 = kt * 32;
        ar = *reinterpret_cast<const f16x8*>(A + (size_t)(m0 + srow) * D + k0 + sc8 * 8);
        br = *reinterpret_cast<const f16x8*>(WoT + (size_t)(n0 + srow) * D + k0 + sc8 * 8);
    };
    auto write_stage = [&](int buf) {
        *reinterpret_cast<f16x8*>(&As[buf][srow][sc8 * 8]) = ar;
        *reinterpret_cast<f16x8*>(&Bs[buf][srow][sc8 * 8]) = br;
    };

    load_stage(0);
    write_stage(0);
    __syncthreads();

    for (int kt = 0; kt < 16; ++kt) {
        const int cur = kt & 1;
        if (kt < 15) load_stage(kt + 1);

        f16x8 af[2], bf[2];
#pragma unroll
        for (int i = 0; i < 2; ++i)
            af[i] = *reinterpret_cast<const f16x8*>(&As[cur][wm * 32 + i * 16 + i16][g * 8]);
#pragma unroll
        for (int j = 0; j < 2; ++j)
            bf[j] = *reinterpret_cast<const f16x8*>(&Bs[cur][wn * 32 + j * 16 + i16][g * 8]);
#pragma unroll
        for (int i = 0; i < 2; ++i)
#pragma unroll
            for (int j = 0; j < 2; ++j)
                acc[i][j] = __builtin_amdgcn_mfma_f32_16x16x32_f16(af[i], bf[j], acc[i][j], 0, 0, 0);

        if (kt < 15) write_stage(cur ^ 1);
        __syncthreads();
    }

    float bvv[2];
#pragma unroll
    for (int j = 0; j < 2; ++j) bvv[j] = bo[n0 + wn * 32 + j * 16 + i16];

#pragma unroll
    for (int i = 0; i < 2; ++i) {
#pragma unroll
        for (int j = 0; j < 2; ++j) {
            const int nn = n0 + wn * 32 + j * 16 + i16;
#pragma unroll
            for (int e = 0; e < 4; ++e) {
                const int mr = m0 + wm * 32 + i * 16 + g * 4 + e;
                out[(size_t)mr * D + nn] = acc[i][j][e] + bvv[j];
            }
        }
    }
}

// ---------------------------------------------------------------------------
extern "C" void kernel_launch(void* const* d_in, const int* in_sizes, int n_in,
                              void* d_out, int out_size, void* d_ws, size_t ws_size,
                              hipStream_t stream)
{
    (void)in_sizes; (void)n_in; (void)out_size; (void)ws_size; // needs ~28 MB of ws

    const float* query = (const float*)d_in[0];
    const float* key_  = (const float*)d_in[1];
    const float* value = (const float*)d_in[2];
    const float* td    = (const float*)d_in[3];
    const float* Wq  = (const float*)d_in[4];  const float* bq  = (const float*)d_in[5];
    const float* Wk  = (const float*)d_in[6];  const float* bk  = (const float*)d_in[7];
    const float* Wv  = (const float*)d_in[8];  const float* bv  = (const float*)d_in[9];
    const float* Wo  = (const float*)d_in[10]; const float* bo  = (const float*)d_in[11];
    const float* Wt1 = (const float*)d_in[12]; const float* bt1 = (const float*)d_in[13];
    const float* Wt2 = (const float*)d_in[14]; const float* bt2 = (const float*)d_in[15];
    float* out = (float*)d_out;

    char* ws = (char*)d_ws;
    f16*   WT   = (f16*)(ws + OFF_WT);
    f16*   q16  = (f16*)(ws + OFF_Q16);
    f16*   k16  = (f16*)(ws + OFF_K16);
    f16*   vT   = (f16*)(ws + OFF_VT);
    f16*   at16 = (f16*)(ws + OFF_AT);
    float* tab  = (float*)(ws + OFF_TAB);
    float* coef = (float*)(ws + OFF_COEF);
    f16*   tdh  = (f16*)(ws + OFF_TDH);

    prep<<<2305, 256, 0, stream>>>(Wq, Wk, Wv, Wo, WT, td, tdh,
                                   Wt1, bt1, Wt2, bt2, tab, coef);
    proj_gemm<<<dim3(32, 8, 3), 256, 0, stream>>>(query, key_, value, WT, bq, bk, bv,
                                                  q16, k16, vT, 0.125f * L2E);
    attn_kernel<<<1024, 256, 0, stream>>>(q16, k16, vT, tdh, tab, coef, at16);
    final_gemm<<<dim3(64, 8), 256, 0, stream>>>(at16, WT + 3ull * (size_t)D * D, bo, out);
}

// Round 9
// 71.762 us; speedup vs baseline: 1.0417x; 1.0417x over previous
//
#include <hip/hip_runtime.h>

typedef _Float16 f16;
typedef _Float16 f16x4 __attribute__((ext_vector_type(4)));
typedef _Float16 f16x8 __attribute__((ext_vector_type(8)));
typedef float f32x4 __attribute__((ext_vector_type(4)));

#define L2E 1.44269504088896340736f

constexpr int D  = 512;
constexpr int S  = 1024;
constexpr int B  = 4;
constexpr int BS = B * S;   // 4096

// workspace layout (bytes); total ~27.3 MB
constexpr size_t OFF_WT   = 0;                               // 4 * 512*512 f16 (WqT,WkT,WvT,WoT)
constexpr size_t OFF_Q16  = OFF_WT  + 4ull * D * D * 2;
constexpr size_t OFF_K16  = OFF_Q16 + (size_t)BS * D * 2;
constexpr size_t OFF_VT   = OFF_K16 + (size_t)BS * D * 2;    // v, transposed: [b*512+n][S]
constexpr size_t OFF_AT   = OFF_VT  + (size_t)BS * D * 2;    // attention output f16 [BS][D]
constexpr size_t OFF_TAB  = OFF_AT  + (size_t)BS * D * 2;    // float [8][1032]
constexpr size_t OFF_COEF = OFF_TAB + 8ull * 1032 * 4;       // float c[8], d[8]; int flag[8]
constexpr size_t OFF_TDH  = OFF_COEF + 256;                  // f16 td, col-permuted, 8.4 MB

// ---------------------------------------------------------------------------
// Kernel 1 "prep": (a) weight transpose+cvt, (b) td f32->f16 col-permuted,
// (c) bias LUT + analytic linearity detection (no atomics).
// grid: [0,256) wtrans | [256,2304) tdconv | 2304 LUT+coef
// ---------------------------------------------------------------------------
__global__ __launch_bounds__(256) void prep(
    const float* __restrict__ Wq, const float* __restrict__ Wk,
    const float* __restrict__ Wv, const float* __restrict__ Wo,
    f16* __restrict__ WT,
    const float* __restrict__ td, f16* __restrict__ tdh,
    const float* __restrict__ Wt1, const float* __restrict__ bt1,
    const float* __restrict__ Wt2, const float* __restrict__ bt2,
    float* __restrict__ tab, float* __restrict__ coef)
{
    __shared__ float tile[64][65];
    __shared__ float w1s[32], b1s[32], w2s[256], b2s[8];

    const int bx = blockIdx.x;
    const int t = threadIdx.x;

    if (bx < 256) {
        // ---- weight transpose ----
        const int z = bx >> 6, xy = bx & 63;
        const float* __restrict__ W = (z == 0) ? Wq : (z == 1) ? Wk : (z == 2) ? Wv : Wo;
        f16* __restrict__ out = WT + (size_t)z * D * D;
        const int k0 = (xy >> 3) * 64, n0 = (xy & 7) * 64;
        for (int i = t; i < 4096; i += 256) {
            int r = i >> 6, c = i & 63;
            tile[r][c] = W[(size_t)(k0 + r) * D + n0 + c];
        }
        __syncthreads();
        for (int i = t; i < 4096; i += 256) {
            int nn = i >> 6, kk = i & 63;
            out[(size_t)(n0 + nn) * D + k0 + kk] = (f16)tile[kk][nn];
        }
    } else if (bx < 2304) {
        // ---- td convert+permute: chunk = 8 dest f16 ----
        const int chunk = (bx - 256) * 256 + t;       // [0, 524288)
        const int row = chunk >> 7;                   // 4096 rows, 128 chunks each
        const int c7 = chunk & 127;
        const int tl = c7 >> 2, gg = c7 & 3;
        const float* __restrict__ src = td + (size_t)row * S + tl * 32;
        float4 a = *reinterpret_cast<const float4*>(src + gg * 4);
        float4 c = *reinterpret_cast<const float4*>(src + 16 + gg * 4);
        f16x8 hv;
        hv[0] = (f16)a.x; hv[1] = (f16)a.y; hv[2] = (f16)a.z; hv[3] = (f16)a.w;
        hv[4] = (f16)c.x; hv[5] = (f16)c.y; hv[6] = (f16)c.z; hv[7] = (f16)c.w;
        *reinterpret_cast<f16x8*>(tdh + (size_t)chunk * 8) = hv;
    } else {
        // ---- bias LUT + coef/flag (no atomics) ----
        if (t < 32) { w1s[t] = Wt1[t]; b1s[t] = bt1[t]; }
        w2s[t] = Wt2[t];
        if (t < 8) b2s[t] = bt2[t];
        __syncthreads();

        const int hh = t >> 5, j = t & 31;

        float f0 = b2s[hh], f1 = b2s[hh];
#pragma unroll 4
        for (int jj = 0; jj < 32; ++jj) {
            float w2 = w2s[jj * 8 + hh];
            f0 += fmaxf(b1s[jj], 0.f) * w2;
            f1 += fmaxf(w1s[jj] + b1s[jj], 0.f) * w2;
        }

        // exact max deviation of the PWL from the chord: check breakpoint u_j
        float devj = 0.f;
        {
            float w1 = w1s[j], b1 = b1s[j];
            float u = (w1 != 0.f) ? (-b1 / w1) : -1.f;
            if (u > 0.f && u < 1.f) {
                float fu = b2s[hh];
#pragma unroll 4
                for (int jj = 0; jj < 32; ++jj)
                    fu += fmaxf(fmaf(u, w1s[jj], b1s[jj]), 0.f) * w2s[jj * 8 + hh];
                devj = fabsf(fu - fmaf(u, f1 - f0, f0)) * L2E;
            }
        }
#pragma unroll
        for (int m = 1; m < 32; m <<= 1)
            devj = fmaxf(devj, __shfl_xor(devj, m));

        if (j == 0) {
            coef[hh]     = (f1 - f0) * L2E;
            coef[8 + hh] = f0 * L2E;
            ((int*)coef)[16 + hh] = (devj < 1e-4f) ? 1 : 0;
        }

        // LUT for the general nonlinear path
        for (int idx = t; idx <= 1024; idx += 256) {
            float tdv = (float)idx * (1.0f / 1024.0f);
            float acc[8];
#pragma unroll
            for (int h2 = 0; h2 < 8; ++h2) acc[h2] = b2s[h2];
#pragma unroll 4
            for (int jj = 0; jj < 32; ++jj) {
                float hvv = fmaxf(fmaf(tdv, w1s[jj], b1s[jj]), 0.f);
#pragma unroll
                for (int h2 = 0; h2 < 8; ++h2) acc[h2] += hvv * w2s[jj * 8 + h2];
            }
#pragma unroll
            for (int h2 = 0; h2 < 8; ++h2)
                tab[h2 * 1032 + idx] = acc[h2] * L2E;
        }
    }
}

// ---------------------------------------------------------------------------
// Kernel 2: fused q/k/v projection GEMM (unchanged).
// ---------------------------------------------------------------------------
__global__ __launch_bounds__(256) void proj_gemm(
    const float* __restrict__ Aq, const float* __restrict__ Ak, const float* __restrict__ Av,
    const f16* __restrict__ WT,
    const float* __restrict__ bq, const float* __restrict__ bk, const float* __restrict__ bv,
    f16* __restrict__ q16, f16* __restrict__ k16, f16* __restrict__ vT, float qscale)
{
    __shared__ f16 As[2][128][40];
    __shared__ f16 Bs[2][64][40];

    const int z = blockIdx.z;
    const float* __restrict__ A    = (z == 0) ? Aq : (z == 1) ? Ak : Av;
    const float* __restrict__ bias = (z == 0) ? bq : (z == 1) ? bk : bv;
    const f16* __restrict__ W      = WT + (size_t)z * D * D;
    const float scale = (z == 0) ? qscale : 1.0f;

    const int t = threadIdx.x;
    const int l = t & 63, w = t >> 6;
    const int i16 = l & 15, g = l >> 4;
    const int wm = w >> 1, wn = w & 1;
    const int m0 = blockIdx.x * 128, n0 = blockIdx.y * 64;

    f32x4 acc[4][2] = {};

    float4 ar[4];
    f16x8  br;
    const int arow = t >> 3, ac4 = t & 7;
    const int brow = t >> 2, bc8 = t & 3;

    auto load_stage = [&](int kt) {
        const int k0 = kt * 32;
#pragma unroll
        for (int r = 0; r < 4; ++r)
            ar[r] = *reinterpret_cast<const float4*>(A + (size_t)(m0 + arow + 32 * r) * D + k0 + ac4 * 4);
        br = *reinterpret_cast<const f16x8*>(W + (size_t)(n0 + brow) * D + k0 + bc8 * 8);
    };
    auto write_stage = [&](int buf) {
#pragma unroll
        for (int r = 0; r < 4; ++r) {
            f16x4 hv;
            hv[0] = (f16)ar[r].x; hv[1] = (f16)ar[r].y; hv[2] = (f16)ar[r].z; hv[3] = (f16)ar[r].w;
            *reinterpret_cast<f16x4*>(&As[buf][arow + 32 * r][ac4 * 4]) = hv;
        }
        *reinterpret_cast<f16x8*>(&Bs[buf][brow][bc8 * 8]) = br;
    };

    load_stage(0);
    write_stage(0);
    __syncthreads();

    for (int kt = 0; kt < 16; ++kt) {
        const int cur = kt & 1;
        if (kt < 15) load_stage(kt + 1);

        f16x8 af[4], bf[2];
#pragma unroll
        for (int i = 0; i < 4; ++i)
            af[i] = *reinterpret_cast<const f16x8*>(&As[cur][wm * 64 + i * 16 + i16][g * 8]);
#pragma unroll
        for (int j = 0; j < 2; ++j)
            bf[j] = *reinterpret_cast<const f16x8*>(&Bs[cur][wn * 32 + j * 16 + i16][g * 8]);
#pragma unroll
        for (int i = 0; i < 4; ++i)
#pragma unroll
            for (int j = 0; j < 2; ++j)
                acc[i][j] = __builtin_amdgcn_mfma_f32_16x16x32_f16(af[i], bf[j], acc[i][j], 0, 0, 0);

        if (kt < 15) write_stage(cur ^ 1);
        __syncthreads();
    }

    float bvv[2];
#pragma unroll
    for (int j = 0; j < 2; ++j) bvv[j] = bias[n0 + wn * 32 + j * 16 + i16];

    if (z < 2) {
        f16* __restrict__ out = (z == 0) ? q16 : k16;
#pragma unroll
        for (int i = 0; i < 4; ++i) {
#pragma unroll
            for (int j = 0; j < 2; ++j) {
                const int nn = n0 + wn * 32 + j * 16 + i16;
#pragma unroll
                for (int e = 0; e < 4; ++e) {
                    const int mr = m0 + wm * 64 + i * 16 + g * 4 + e;
                    out[(size_t)mr * D + nn] = (f16)((acc[i][j][e] + bvv[j]) * scale);
                }
            }
        }
    } else {
#pragma unroll
        for (int i = 0; i < 4; ++i) {
            const int mr = m0 + wm * 64 + i * 16 + g * 4;
            const int bb = mr >> 10, jj = mr & 1023;
#pragma unroll
            for (int j = 0; j < 2; ++j) {
                const int nn = n0 + wn * 32 + j * 16 + i16;
                f16x4 hv;
#pragma unroll
                for (int e = 0; e < 4; ++e) hv[e] = (f16)(acc[i][j][e] + bvv[j]);
                *reinterpret_cast<f16x4*>(vT + ((size_t)(bb * D + nn)) * S + jj) = hv;
            }
        }
    }
}

// ---------------------------------------------------------------------------
// Kernel 3: fused flash attention with temporal bias.
// R8: attn time tracks total staged K/V bytes (R2/R4/R5/R7 ~270MB ~41us;
// R3 524MB 79us) at ~6.5 TB/s -- a serving-rate ceiling for this pattern.
// So: halve the bytes.  Block = 512 thr (8 waves) = 64 q-rows x KV-split-2:
// waves 0-3 cover KV half 0, waves 4-7 half 1, 16 rows each; one 16KB K/V
// stage per block-iter serves 64 rows -> staged K/V 268->134 MB.
// Grid 512 = 2 blocks/CU = 16 waves/CU.  Flash-decoding merge pairs (w,w+4).
// ---------------------------------------------------------------------------
__global__ __launch_bounds__(512, 4) void attn_kernel(
    const f16* __restrict__ q16, const f16* __restrict__ k16, const f16* __restrict__ vT,
    const f16* __restrict__ tdh, const float* __restrict__ tabg, const float* __restrict__ coef,
    f16* __restrict__ out16)
{
    __shared__ __align__(16) f16 Ks[2][2][2048];   // [dbuf][half][32*64]
    __shared__ __align__(16) f16 Vs[2][2][2048];   // [dbuf][half][64*32]
    __shared__ __align__(16) f16 Ps[8][512];
    __shared__ float obuf[4][16][68];              // merge buffer (pairs)
    __shared__ float mlb[4][2][16];                // [pair][m|l][row]

    const int bid = blockIdx.x;
    const int b  = bid & 3;
    const int h  = (bid >> 2) & 7;
    const int qt = bid >> 5;                 // [0,16)

    const int t = threadIdx.x;
    const int w = t >> 6, l = t & 63;
    const int i16 = l & 15, g = l >> 4;
    const int half = w >> 2, pr = w & 3;
    const int qrow = qt * 64 + pr * 16 + i16;

    const float cH = coef[h], dH = coef[8 + h];
    const int lin = ((const int*)coef)[16 + h];
    const float* __restrict__ th = tabg + h * 1032;

    f16x8 qf[2];
#pragma unroll
    for (int kf = 0; kf < 2; ++kf)
        qf[kf] = *reinterpret_cast<const f16x8*>(
            q16 + (size_t)(b * S + qrow) * D + h * 64 + kf * 32 + g * 8);

    float mr = -1e30f, lr = 0.f;
    f32x4 o[4] = {};

    // staging: 512 threads, each 1 K-chunk + 1 V-chunk (16B) for half kh=t>>8
    const int kh   = t >> 8;
    const int krow = (t >> 3) & 31, kc8 = t & 7;
    const int vdv  = (t >> 2) & 63, vj8 = t & 3;
    const int kofs = krow * 64 + ((kc8 ^ (krow & 7)) << 3);
    const int vofs = vdv * 32 + ((vj8 ^ (vdv & 3)) << 3);
    f16x8 sk, sv;

    auto stage_load = [&](int jt) {
        sk = *reinterpret_cast<const f16x8*>(
            k16 + (size_t)(b * S + kh * 512 + jt * 32 + krow) * D + h * 64 + kc8 * 8);
        sv = *reinterpret_cast<const f16x8*>(
            vT + (size_t)(b * D + h * 64 + vdv) * S + kh * 512 + jt * 32 + vj8 * 8);
    };
    auto stage_write = [&](int buf) {
        *reinterpret_cast<f16x8*>(&Ks[buf][kh][kofs]) = sk;
        *reinterpret_cast<f16x8*>(&Vs[buf][kh][vofs]) = sv;
    };

    // swizzled LDS read offsets
    int kro0[2], kro1[2], vro[4];
#pragma unroll
    for (int fj = 0; fj < 2; ++fj) {
        const int rj = fj * 16 + i16;
        kro0[fj] = rj * 64 + ((g ^ (i16 & 7)) << 3);
        kro1[fj] = rj * 64 + (((g + 4) ^ (i16 & 7)) << 3);
    }
#pragma unroll
    for (int fv = 0; fv < 4; ++fv)
        vro[fv] = (fv * 16 + i16) * 32 + ((g ^ (i16 & 3)) << 3);

    const int q2  = (i16 >> 1) & 3;
    const int pw0 = i16 * 32 + ((((g >> 1)    ) ^ q2) << 3) + ((g & 1) << 2);
    const int pw1 = i16 * 32 + ((((g >> 1) + 2) ^ q2) << 3) + ((g & 1) << 2);
    const int prd = i16 * 32 + ((g ^ q2) << 3);

    const f16* __restrict__ tdp = tdh + (size_t)(b * S + qrow) * S + half * 512 + g * 8;
    f16x8 tcur, tnext;

    stage_load(0);
    tcur = *reinterpret_cast<const f16x8*>(tdp);
    stage_write(0);
    __syncthreads();

    for (int jt = 0; jt < 16; ++jt) {
        const int cur = jt & 1;
        if (jt < 15) {
            stage_load(jt + 1);
            tnext = *reinterpret_cast<const f16x8*>(tdp + (jt + 1) * 32);
        }

        // ---- S^T = K * Q^T ----
        f32x4 s[2];
#pragma unroll
        for (int fj = 0; fj < 2; ++fj) {
            f16x8 ka0 = *reinterpret_cast<const f16x8*>(&Ks[cur][half][kro0[fj]]);
            f16x8 ka1 = *reinterpret_cast<const f16x8*>(&Ks[cur][half][kro1[fj]]);
            f32x4 zz = {0.f, 0.f, 0.f, 0.f};
            zz = __builtin_amdgcn_mfma_f32_16x16x32_f16(ka0, qf[0], zz, 0, 0, 0);
            s[fj] = __builtin_amdgcn_mfma_f32_16x16x32_f16(ka1, qf[1], zz, 0, 0, 0);
        }

        // ---- bias + online softmax (per-lane q-row i16) ----
        float pvv[2][4];
        float tmax = -1e30f;
#pragma unroll
        for (int fj = 0; fj < 2; ++fj)
#pragma unroll
            for (int e = 0; e < 4; ++e) {
                float u = (float)tcur[fj * 4 + e];
                float vsc;
                if (lin) {
                    vsc = fmaf(u, cH, s[fj][e] + dH);
                } else {
                    float x = fminf(fmaxf(u, 0.f), 1.f) * 1024.f;
                    int ix = (int)x;
                    ix = (ix > 1023) ? 1023 : ix;
                    float fr = x - (float)ix;
                    float t0v = th[ix], t1v = th[ix + 1];
                    vsc = s[fj][e] + fmaf(fr, t1v - t0v, t0v);
                }
                pvv[fj][e] = vsc;
                tmax = fmaxf(tmax, vsc);
            }
        tmax = fmaxf(tmax, __shfl_xor(tmax, 16));
        tmax = fmaxf(tmax, __shfl_xor(tmax, 32));
        if (__any(tmax > mr)) {
            float mnew = fmaxf(mr, tmax);
            float alpha = exp2f(mr - mnew);
            mr = mnew;
            lr *= alpha;
#pragma unroll
            for (int fv = 0; fv < 4; ++fv) o[fv] *= alpha;
        }

        float rsum = 0.f;
        f16x4 pq[2];
#pragma unroll
        for (int fj = 0; fj < 2; ++fj)
#pragma unroll
            for (int e = 0; e < 4; ++e) {
                float p = exp2f(pvv[fj][e] - mr);
                rsum += p;
                pq[fj][e] = (f16)p;
            }
        rsum += __shfl_xor(rsum, 16);
        rsum += __shfl_xor(rsum, 32);
        lr += rsum;

        f16* ps = Ps[w];
        *reinterpret_cast<f16x4*>(ps + pw0) = pq[0];
        *reinterpret_cast<f16x4*>(ps + pw1) = pq[1];
        f16x8 pb = *reinterpret_cast<const f16x8*>(ps + prd);

        // ---- out^T += V^T * P^T ----
#pragma unroll
        for (int fv = 0; fv < 4; ++fv) {
            f16x8 va = *reinterpret_cast<const f16x8*>(&Vs[cur][half][vro[fv]]);
            o[fv] = __builtin_amdgcn_mfma_f32_16x16x32_f16(va, pb, o[fv], 0, 0, 0);
        }

        if (jt < 15) stage_write(cur ^ 1);
        __syncthreads();
        tcur = tnext;
    }

    // ---- merge halves (flash-decoding combine), then store ----
    if (half == 1) {
#pragma unroll
        for (int fv = 0; fv < 4; ++fv)
            *reinterpret_cast<f32x4*>(&obuf[pr][i16][fv * 16 + g * 4]) = o[fv];
        if (g == 0) { mlb[pr][0][i16] = mr; mlb[pr][1][i16] = lr; }
    }
    __syncthreads();
    if (half == 0) {
        const float m1 = mlb[pr][0][i16], l1 = mlb[pr][1][i16];
        const float mm = fmaxf(mr, m1);
        const float a0 = exp2f(mr - mm), a1 = exp2f(m1 - mm);
        const float inv = 1.0f / (lr * a0 + l1 * a1);
#pragma unroll
        for (int fv = 0; fv < 4; ++fv) {
            f32x4 o1 = *reinterpret_cast<const f32x4*>(&obuf[pr][i16][fv * 16 + g * 4]);
            f16x4 hv;
#pragma unroll
            for (int e = 0; e < 4; ++e) hv[e] = (f16)((o[fv][e] * a0 + o1[e] * a1) * inv);
            *reinterpret_cast<f16x4*>(
                out16 + (size_t)(b * S + qrow) * D + h * 64 + fv * 16 + g * 4) = hv;
        }
    }
}

// ---------------------------------------------------------------------------
// Kernel 4: output projection (unchanged).
// ---------------------------------------------------------------------------
__global__ __launch_bounds__(256) void final_gemm(const f16* __restrict__ A, const f16* __restrict__ WoT,
                                                  const float* __restrict__ bo, float* __restrict__ out)
{
    __shared__ f16 As[2][64][40];
    __shared__ f16 Bs[2][64][40];

    const int t = threadIdx.x;
    const int l = t & 63, w = t >> 6;
    const int i16 = l & 15, g = l >> 4;
    const int wm = w >> 1, wn = w & 1;
    const int m0 = blockIdx.x * 64, n0 = blockIdx.y * 64;

    f32x4 acc[2][2] = {};
    f16x8 ar, br;
    const int srow = t >> 2, sc8 = t & 3;

    auto load_stage = [&](int kt) {
        const int k0 = kt * 32;
        ar = *reinterpret_cast<const f16x8*>(A + (size_t)(m0 + srow) * D + k0 + sc8 * 8);
        br = *reinterpret_cast<const f16x8*>(WoT + (size_t)(n0 + srow) * D + k0 + sc8 * 8);
    };
    auto write_stage = [&](int buf) {
        *reinterpret_cast<f16x8*>(&As[buf][srow][sc8 * 8]) = ar;
        *reinterpret_cast<f16x8*>(&Bs[buf][srow][sc8 * 8]) = br;
    };

    load_stage(0);
    write_stage(0);
    __syncthreads();

    for (int kt = 0; kt < 16; ++kt) {
        const int cur = kt & 1;
        if (kt < 15) load_stage(kt + 1);

        f16x8 af[2], bf[2];
#pragma unroll
        for (int i = 0; i < 2; ++i)
            af[i] = *reinterpret_cast<const f16x8*>(&As[cur][wm * 32 + i * 16 + i16][g * 8]);
#pragma unroll
        for (int j = 0; j < 2; ++j)
            bf[j] = *reinterpret_cast<const f16x8*>(&Bs[cur][wn * 32 + j * 16 + i16][g * 8]);
#pragma unroll
        for (int i = 0; i < 2; ++i)
#pragma unroll
            for (int j = 0; j < 2; ++j)
                acc[i][j] = __builtin_amdgcn_mfma_f32_16x16x32_f16(af[i], bf[j], acc[i][j], 0, 0, 0);

        if (kt < 15) write_stage(cur ^ 1);
        __syncthreads();
    }

    float bvv[2];
#pragma unroll
    for (int j = 0; j < 2; ++j) bvv[j] = bo[n0 + wn * 32 + j * 16 + i16];

#pragma unroll
    for (int i = 0; i < 2; ++i) {
#pragma unroll
        for (int j = 0; j < 2; ++j) {
            const int nn = n0 + wn * 32 + j * 16 + i16;
#pragma unroll
            for (int e = 0; e < 4; ++e) {
                const int mr = m0 + wm * 32 + i * 16 + g * 4 + e;
                out[(size_t)mr * D + nn] = acc[i][j][e] + bvv[j];
            }
        }
    }
}

// ---------------------------------------------------------------------------
extern "C" void kernel_launch(void* const* d_in, const int* in_sizes, int n_in,
                              void* d_out, int out_size, void* d_ws, size_t ws_size,
                              hipStream_t stream)
{
    (void)in_sizes; (void)n_in; (void)out_size; (void)ws_size; // needs ~28 MB of ws

    const float* query = (const float*)d_in[0];
    const float* key_  = (const float*)d_in[1];
    const float* value = (const float*)d_in[2];
    const float* td    = (const float*)d_in[3];
    const float* Wq  = (const float*)d_in[4];  const float* bq  = (const float*)d_in[5];
    const float* Wk  = (const float*)d_in[6];  const float* bk  = (const float*)d_in[7];
    const float* Wv  = (const float*)d_in[8];  const float* bv  = (const float*)d_in[9];
    const float* Wo  = (const float*)d_in[10]; const float* bo  = (const float*)d_in[11];
    const float* Wt1 = (const float*)d_in[12]; const float* bt1 = (const float*)d_in[13];
    const float* Wt2 = (const float*)d_in[14]; const float* bt2 = (const float*)d_in[15];
    float* out = (float*)d_out;

    char* ws = (char*)d_ws;
    f16*   WT   = (f16*)(ws + OFF_WT);
    f16*   q16  = (f16*)(ws + OFF_Q16);
    f16*   k16  = (f16*)(ws + OFF_K16);
    f16*   vT   = (f16*)(ws + OFF_VT);
    f16*   at16 = (f16*)(ws + OFF_AT);
    float* tab  = (float*)(ws + OFF_TAB);
    float* coef = (float*)(ws + OFF_COEF);
    f16*   tdh  = (f16*)(ws + OFF_TDH);

    prep<<<2305, 256, 0, stream>>>(Wq, Wk, Wv, Wo, WT, td, tdh,
                                   Wt1, bt1, Wt2, bt2, tab, coef);
    proj_gemm<<<dim3(32, 8, 3), 256, 0, stream>>>(query, key_, value, WT, bq, bk, bv,
                                                  q16, k16, vT, 0.125f * L2E);
    attn_kernel<<<512, 512, 0, stream>>>(q16, k16, vT, tdh, tab, coef, at16);
    final_gemm<<<dim3(64, 8), 256, 0, stream>>>(at16, WT + 3ull * (size_t)D * D, bo, out);
}